// Round 2
// baseline (437.134 us; speedup 1.0000x reference)
//
#include <hip/hip_runtime.h>

#define EMBED 1024
#define THREE_EMBED 3072
#define HEADS 16
#define HDIM 64
#define SEQ 2048
#define BATCH 2
#define MTOT 4096  // B*T

typedef short bf16x8 __attribute__((ext_vector_type(8)));
typedef float f32x4 __attribute__((ext_vector_type(4)));

__device__ __forceinline__ unsigned short f2bf(float f) {
  union { float f; unsigned int u; } v; v.f = f;
  unsigned int r = v.u + 0x7fffu + ((v.u >> 16) & 1u);
  return (unsigned short)(r >> 16);
}

// ---------------- transpose fp32 [K][N] -> bf16 [N][K] ----------------
__global__ __launch_bounds__(256) void k_transpose_bf16(
    const float* __restrict__ in, unsigned short* __restrict__ out, int K, int N) {
  __shared__ float t[32][33];
  int tx = threadIdx.x & 31, ty = threadIdx.x >> 5;
  int n0 = blockIdx.x * 32, k0 = blockIdx.y * 32;
#pragma unroll
  for (int i = 0; i < 32; i += 8)
    t[ty + i][tx] = in[(size_t)(k0 + ty + i) * N + n0 + tx];
  __syncthreads();
#pragma unroll
  for (int i = 0; i < 32; i += 8)
    out[(size_t)(n0 + ty + i) * K + k0 + tx] = f2bf(t[tx][ty + i]);
}

// ---------------- layernorm fp32 [4096][1024] -> bf16 ----------------
__global__ __launch_bounds__(256) void k_layernorm(
    const float* __restrict__ x, const float* __restrict__ g,
    const float* __restrict__ b, unsigned short* __restrict__ out) {
  int row = blockIdx.x;
  int tid = threadIdx.x;
  const float4 xv = *(const float4*)(x + (size_t)row * EMBED + tid * 4);
  float s = xv.x + xv.y + xv.z + xv.w;
  float sq = xv.x * xv.x + xv.y * xv.y + xv.z * xv.z + xv.w * xv.w;
#pragma unroll
  for (int off = 1; off < 64; off <<= 1) {
    s += __shfl_xor(s, off);
    sq += __shfl_xor(sq, off);
  }
  __shared__ float red[8];
  int w = tid >> 6;
  if ((tid & 63) == 0) { red[w] = s; red[4 + w] = sq; }
  __syncthreads();
  s = red[0] + red[1] + red[2] + red[3];
  sq = red[4] + red[5] + red[6] + red[7];
  float mu = s * (1.0f / EMBED);
  float var = sq * (1.0f / EMBED) - mu * mu;
  float rs = rsqrtf(var + 1e-5f);
  float xs[4] = {xv.x, xv.y, xv.z, xv.w};
  unsigned short o[4];
#pragma unroll
  for (int c = 0; c < 4; c++) {
    int col = tid * 4 + c;
    o[c] = f2bf((xs[c] - mu) * rs * g[col] + b[col]);
  }
  *(ushort4*)(out + (size_t)row * EMBED + tid * 4) = *(const ushort4*)o;
}

// ---------------- bf16 MFMA GEMM: C = A[M,K] @ Bt[N,K]^T ----------------
// EPI 0: +bias -> bf16 out     (QKV)
// EPI 1: +bias +resid -> f32   (proj, fc2)
// EPI 2: +bias, GELU -> bf16   (fc1)
template <int EPI>
__global__ __launch_bounds__(256) void k_gemm(
    const unsigned short* __restrict__ A, const unsigned short* __restrict__ Bt,
    const float* __restrict__ bias, const float* __restrict__ resid,
    float* __restrict__ outf, unsigned short* __restrict__ outb,
    int M, int N, int K) {
  __shared__ unsigned short lA[128][40];
  __shared__ unsigned short lB[128][40];
  int tid = threadIdx.x;
  int m0 = blockIdx.y * 128, n0 = blockIdx.x * 128;
  int lane = tid & 63, w = tid >> 6;
  int wm = (w >> 1) * 64, wn = (w & 1) * 64;
  int lr = lane & 15, lg = lane >> 4;
  f32x4 acc[4][4] = {};
  int srow = tid >> 2, sc8 = (tid & 3) * 8;  // 64 rows x 32 cols per pass; 2 passes
  const unsigned short* Ap = A + (size_t)(m0 + srow) * K + sc8;
  const unsigned short* Bp = Bt + (size_t)(n0 + srow) * K + sc8;
  for (int k0 = 0; k0 < K; k0 += 32) {
    uint4 av0 = *(const uint4*)(Ap + k0);
    uint4 av1 = *(const uint4*)(Ap + (size_t)64 * K + k0);
    uint4 bv0 = *(const uint4*)(Bp + k0);
    uint4 bv1 = *(const uint4*)(Bp + (size_t)64 * K + k0);
    __syncthreads();
    *(uint4*)&lA[srow][sc8] = av0;
    *(uint4*)&lA[srow + 64][sc8] = av1;
    *(uint4*)&lB[srow][sc8] = bv0;
    *(uint4*)&lB[srow + 64][sc8] = bv1;
    __syncthreads();
    bf16x8 af[4], bfr[4];
#pragma unroll
    for (int i = 0; i < 4; i++) {
      af[i] = *(const bf16x8*)&lA[wm + i * 16 + lr][lg * 8];
      bfr[i] = *(const bf16x8*)&lB[wn + i * 16 + lr][lg * 8];
    }
#pragma unroll
    for (int i = 0; i < 4; i++)
#pragma unroll
      for (int j = 0; j < 4; j++)
        acc[i][j] = __builtin_amdgcn_mfma_f32_16x16x32_bf16(af[i], bfr[j], acc[i][j], 0, 0, 0);
  }
#pragma unroll
  for (int i = 0; i < 4; i++) {
#pragma unroll
    for (int j = 0; j < 4; j++) {
      int colb = n0 + wn + j * 16 + lr;
      float bv = bias[colb];
#pragma unroll
      for (int r = 0; r < 4; r++) {
        int row = m0 + wm + i * 16 + lg * 4 + r;
        float v = acc[i][j][r] + bv;
        size_t idx = (size_t)row * N + colb;
        if constexpr (EPI == 0) {
          outb[idx] = f2bf(v);
        } else if constexpr (EPI == 1) {
          outf[idx] = v + resid[idx];
        } else {
          float gv = 0.5f * v * (1.0f + erff(v * 0.70710678118654752f));
          outb[idx] = f2bf(gv);
        }
      }
    }
  }
}

// ---------------- causal flash attention ----------------
// qkv bf16 [B*T][3072] (Q|K|V, head h at cols h*64). out bf16 [B*T][1024].
// grid: x = q-tile (64 rows), y = b*16+h. 4 waves, 16 q-rows each.
__global__ __launch_bounds__(256) void k_attention(
    const unsigned short* __restrict__ qkv, unsigned short* __restrict__ out) {
  __shared__ unsigned short lK[64][72];
  __shared__ unsigned short lV[72][72];  // transposed: lV[d][key] (rows padded)
  __shared__ unsigned short lP[4][16][72];
  int qt = blockIdx.x;
  int bh = blockIdx.y;
  int b = bh >> 4, h = bh & 15;
  int tid = threadIdx.x, lane = tid & 63, w = tid >> 6;
  int lr = lane & 15, lg = lane >> 4;
  const unsigned short* base = qkv + (size_t)b * SEQ * THREE_EMBED + h * HDIM;
  const unsigned short* Kb = base + EMBED;
  const unsigned short* Vb = base + 2 * EMBED;
  int qrow = qt * 64 + w * 16 + lr;
  bf16x8 qf[2];
  qf[0] = *(const bf16x8*)(base + (size_t)qrow * THREE_EMBED + lg * 8);
  qf[1] = *(const bf16x8*)(base + (size_t)qrow * THREE_EMBED + 32 + lg * 8);
  f32x4 o[4] = {};
  float m_[4] = {-INFINITY, -INFINITY, -INFINITY, -INFINITY};
  float l_[4] = {0.f, 0.f, 0.f, 0.f};
  for (int kt = 0; kt <= qt; kt++) {
    __syncthreads();
    for (int c = tid; c < 512; c += 256) {
      int r = c >> 3, c8 = (c & 7) * 8;
      *(uint4*)&lK[r][c8] = *(const uint4*)(Kb + (size_t)(kt * 64 + r) * THREE_EMBED + c8);
      uint4 vv = *(const uint4*)(Vb + (size_t)(kt * 64 + r) * THREE_EMBED + c8);
      unsigned short* u = (unsigned short*)&vv;
#pragma unroll
      for (int j = 0; j < 8; j++) lV[c8 + j][r] = u[j];
    }
    __syncthreads();
    f32x4 s[4];
#pragma unroll
    for (int ct = 0; ct < 4; ct++) {
      bf16x8 k0 = *(const bf16x8*)&lK[ct * 16 + lr][lg * 8];
      bf16x8 k1 = *(const bf16x8*)&lK[ct * 16 + lr][32 + lg * 8];
      f32x4 z = {};
      z = __builtin_amdgcn_mfma_f32_16x16x32_bf16(qf[0], k0, z, 0, 0, 0);
      s[ct] = __builtin_amdgcn_mfma_f32_16x16x32_bf16(qf[1], k1, z, 0, 0, 0);
    }
    bool diag = (kt == qt);
    float mx[4] = {-INFINITY, -INFINITY, -INFINITY, -INFINITY};
#pragma unroll
    for (int ct = 0; ct < 4; ct++) {
#pragma unroll
      for (int r = 0; r < 4; r++) {
        float sv = s[ct][r] * 0.125f;  // exact 1/sqrt(64)
        if (diag) {
          int kj = ct * 16 + lr;
          int qi = w * 16 + lg * 4 + r;
          if (kj > qi) sv = -INFINITY;
        }
        s[ct][r] = sv;
        mx[r] = fmaxf(mx[r], sv);
      }
    }
#pragma unroll
    for (int r = 0; r < 4; r++) {
#pragma unroll
      for (int off = 1; off < 16; off <<= 1)
        mx[r] = fmaxf(mx[r], __shfl_xor(mx[r], off));
    }
    float al[4], ps[4];
#pragma unroll
    for (int r = 0; r < 4; r++) {
      float mn = fmaxf(m_[r], mx[r]);
      al[r] = expf(m_[r] - mn);
      m_[r] = mn;
      ps[r] = 0.f;
    }
#pragma unroll
    for (int ct = 0; ct < 4; ct++)
#pragma unroll
      for (int r = 0; r < 4; r++) {
        float p = expf(s[ct][r] - m_[r]);
        s[ct][r] = p;
        ps[r] += p;
      }
#pragma unroll
    for (int r = 0; r < 4; r++) {
#pragma unroll
      for (int off = 1; off < 16; off <<= 1) ps[r] += __shfl_xor(ps[r], off);
      l_[r] = l_[r] * al[r] + ps[r];
    }
#pragma unroll
    for (int dt = 0; dt < 4; dt++)
#pragma unroll
      for (int r = 0; r < 4; r++) o[dt][r] *= al[r];
#pragma unroll
    for (int ct = 0; ct < 4; ct++)
#pragma unroll
      for (int r = 0; r < 4; r++)
        lP[w][lg * 4 + r][ct * 16 + lr] = f2bf(s[ct][r]);
#pragma unroll
    for (int ks = 0; ks < 2; ks++) {
      bf16x8 pf = *(const bf16x8*)&lP[w][lr][ks * 32 + lg * 8];
#pragma unroll
      for (int dt = 0; dt < 4; dt++) {
        bf16x8 vf = *(const bf16x8*)&lV[dt * 16 + lr][ks * 32 + lg * 8];
        o[dt] = __builtin_amdgcn_mfma_f32_16x16x32_bf16(pf, vf, o[dt], 0, 0, 0);
      }
    }
  }
#pragma unroll
  for (int dt = 0; dt < 4; dt++) {
#pragma unroll
    for (int r = 0; r < 4; r++) {
      int row = qt * 64 + w * 16 + lg * 4 + r;
      float val = o[dt][r] / l_[r];
      out[(size_t)(b * SEQ + row) * EMBED + h * HDIM + dt * 16 + lr] = f2bf(val);
    }
  }
}

extern "C" void kernel_launch(void* const* d_in, const int* in_sizes, int n_in,
                              void* d_out, int out_size, void* d_ws, size_t ws_size,
                              hipStream_t stream) {
  const float* x      = (const float*)d_in[0];
  const float* ln1_g  = (const float*)d_in[1];
  const float* ln1_b  = (const float*)d_in[2];
  const float* w_attn = (const float*)d_in[3];
  const float* b_attn = (const float*)d_in[4];
  const float* w_proj = (const float*)d_in[5];
  const float* b_proj = (const float*)d_in[6];
  const float* ln2_g  = (const float*)d_in[7];
  const float* ln2_b  = (const float*)d_in[8];
  const float* w_fc   = (const float*)d_in[9];
  const float* b_fc   = (const float*)d_in[10];
  const float* w_fc2  = (const float*)d_in[11];
  const float* b_fc2  = (const float*)d_in[12];
  float* outp = (float*)d_out;

  char* ws = (char*)d_ws;
  unsigned short* wT_attn = (unsigned short*)(ws);             // [3072][1024] bf16, 6 MB
  unsigned short* wT_proj = (unsigned short*)(ws + 6291456);   // [1024][1024] bf16, 2 MB
  unsigned short* wT_fc   = (unsigned short*)(ws + 8388608);   // [4096][1024] bf16, 8 MB
  unsigned short* wT_fc2  = (unsigned short*)(ws + 16777216);  // [1024][4096] bf16, 8 MB
  unsigned short* buf1    = (unsigned short*)(ws + 25165824);  // 8 MB: xln -> attnout -> x2ln
  float*          x1      = (float*)(ws + 33554432);           // 16 MB fp32
  unsigned short* qkv_h   = (unsigned short*)(ws + 50331648);  // 24 MB: qkv bf16 -> h bf16
  // total ws use: 72 MB

  dim3 blk(256);
  // weight transposes (fp32 -> bf16, [K][N] -> [N][K])
  k_transpose_bf16<<<dim3(3072 / 32, 1024 / 32), blk, 0, stream>>>(w_attn, wT_attn, 1024, 3072);
  k_transpose_bf16<<<dim3(1024 / 32, 1024 / 32), blk, 0, stream>>>(w_proj, wT_proj, 1024, 1024);
  k_transpose_bf16<<<dim3(4096 / 32, 1024 / 32), blk, 0, stream>>>(w_fc, wT_fc, 1024, 4096);
  k_transpose_bf16<<<dim3(1024 / 32, 4096 / 32), blk, 0, stream>>>(w_fc2, wT_fc2, 4096, 1024);
  // LN1: x -> xln (buf1)
  k_layernorm<<<dim3(MTOT), blk, 0, stream>>>(x, ln1_g, ln1_b, buf1);
  // QKV: xln @ w_attn + b_attn -> qkv bf16
  k_gemm<0><<<dim3(THREE_EMBED / 128, MTOT / 128), blk, 0, stream>>>(
      buf1, wT_attn, b_attn, nullptr, nullptr, qkv_h, MTOT, THREE_EMBED, EMBED);
  // attention -> attnout (buf1)
  k_attention<<<dim3(SEQ / 64, BATCH * HEADS), blk, 0, stream>>>(qkv_h, buf1);
  // proj + residual: x1 = x + attnout @ w_proj + b_proj
  k_gemm<1><<<dim3(EMBED / 128, MTOT / 128), blk, 0, stream>>>(
      buf1, wT_proj, b_proj, x, x1, nullptr, MTOT, EMBED, EMBED);
  // LN2: x1 -> x2ln (buf1)
  k_layernorm<<<dim3(MTOT), blk, 0, stream>>>(x1, ln2_g, ln2_b, buf1);
  // FC1 + GELU: h = gelu(x2ln @ w_fc + b_fc) -> qkv_h
  k_gemm<2><<<dim3(4 * EMBED / 128, MTOT / 128), blk, 0, stream>>>(
      buf1, wT_fc, b_fc, nullptr, nullptr, qkv_h, MTOT, 4 * EMBED, EMBED);
  // FC2 + residual: out = x1 + h @ w_fc2 + b_fc2
  k_gemm<1><<<dim3(EMBED / 128, MTOT / 128), blk, 0, stream>>>(
      qkv_h, wT_fc2, b_fc2, x1, outp, nullptr, MTOT, EMBED, 4 * EMBED);
}

// Round 3
// 387.906 us; speedup vs baseline: 1.1269x; 1.1269x over previous
//
#include <hip/hip_runtime.h>

#define EMBED 1024
#define THREE_EMBED 3072
#define HEADS 16
#define HDIM 64
#define SEQ 2048
#define BATCH 2
#define MTOT 4096  // B*T
#define QBLK 128

typedef short bf16x8 __attribute__((ext_vector_type(8)));
typedef float f32x4 __attribute__((ext_vector_type(4)));

#define MFMA16(a, b, c) __builtin_amdgcn_mfma_f32_16x16x32_bf16(a, b, c, 0, 0, 0)

__device__ __forceinline__ unsigned short f2bf(float f) {
  union { float f; unsigned int u; } v; v.f = f;
  unsigned int r = v.u + 0x7fffu + ((v.u >> 16) & 1u);
  return (unsigned short)(r >> 16);
}

// async 16B global->LDS. lds dest must be wave-uniform-base semantics (HW: base + lane*16).
__device__ __forceinline__ void gload_lds16(const unsigned short* g, unsigned short* l) {
  __builtin_amdgcn_global_load_lds(
      (const __attribute__((address_space(1))) void*)g,
      (__attribute__((address_space(3))) void*)l, 16, 0, 0);
}

// ---------------- transpose fp32 [K][N] -> bf16 [N][K] ----------------
__global__ __launch_bounds__(256) void k_transpose_bf16(
    const float* __restrict__ in, unsigned short* __restrict__ out, int K, int N) {
  __shared__ float t[32][33];
  int tx = threadIdx.x & 31, ty = threadIdx.x >> 5;
  int n0 = blockIdx.x * 32, k0 = blockIdx.y * 32;
#pragma unroll
  for (int i = 0; i < 32; i += 8)
    t[ty + i][tx] = in[(size_t)(k0 + ty + i) * N + n0 + tx];
  __syncthreads();
#pragma unroll
  for (int i = 0; i < 32; i += 8)
    out[(size_t)(n0 + ty + i) * K + k0 + tx] = f2bf(t[tx][ty + i]);
}

// ---------------- V transpose: qkv V-part -> Vt[bh][64][2048] bf16 ----------------
__global__ __launch_bounds__(256) void k_transpose_v(
    const unsigned short* __restrict__ qkv, unsigned short* __restrict__ Vt) {
  __shared__ unsigned short t[32][33];
  int tx = threadIdx.x & 31, ty = threadIdx.x >> 5;  // 32 x 8
  int t0 = blockIdx.x * 32;
  int d0 = (blockIdx.y & 1) * 32;
  int bh = blockIdx.y >> 1;
  int b = bh >> 4, h = bh & 15;
  const unsigned short* src = qkv + (size_t)b * SEQ * THREE_EMBED + 2 * EMBED + h * HDIM;
#pragma unroll
  for (int i = 0; i < 32; i += 8)
    t[ty + i][tx] = src[(size_t)(t0 + ty + i) * THREE_EMBED + d0 + tx];
  __syncthreads();
  unsigned short* dst = Vt + (size_t)bh * HDIM * SEQ;
#pragma unroll
  for (int i = 0; i < 32; i += 8)
    dst[(size_t)(d0 + ty + i) * SEQ + t0 + tx] = t[tx][ty + i];
}

// ---------------- layernorm fp32 [4096][1024] -> bf16 ----------------
__global__ __launch_bounds__(256) void k_layernorm(
    const float* __restrict__ x, const float* __restrict__ g,
    const float* __restrict__ b, unsigned short* __restrict__ out) {
  int row = blockIdx.x;
  int tid = threadIdx.x;
  const float4 xv = *(const float4*)(x + (size_t)row * EMBED + tid * 4);
  float s = xv.x + xv.y + xv.z + xv.w;
  float sq = xv.x * xv.x + xv.y * xv.y + xv.z * xv.z + xv.w * xv.w;
#pragma unroll
  for (int off = 1; off < 64; off <<= 1) {
    s += __shfl_xor(s, off);
    sq += __shfl_xor(sq, off);
  }
  __shared__ float red[8];
  int w = tid >> 6;
  if ((tid & 63) == 0) { red[w] = s; red[4 + w] = sq; }
  __syncthreads();
  s = red[0] + red[1] + red[2] + red[3];
  sq = red[4] + red[5] + red[6] + red[7];
  float mu = s * (1.0f / EMBED);
  float var = sq * (1.0f / EMBED) - mu * mu;
  float rs = rsqrtf(var + 1e-5f);
  float xs[4] = {xv.x, xv.y, xv.z, xv.w};
  unsigned short o[4];
#pragma unroll
  for (int c = 0; c < 4; c++) {
    int col = tid * 4 + c;
    o[c] = f2bf((xs[c] - mu) * rs * g[col] + b[col]);
  }
  *(ushort4*)(out + (size_t)row * EMBED + tid * 4) = *(const ushort4*)o;
}

// ---------------- bf16 MFMA GEMM (m97 structure): C = A[M,K] @ Bt[N,K]^T ----------------
// EPI 0: +bias -> bf16 out     (QKV)
// EPI 1: +bias +resid -> f32   (proj, fc2)
// EPI 2: +bias, GELU -> bf16   (fc1)
template <int EPI>
__global__ __launch_bounds__(256) void k_gemm(
    const unsigned short* __restrict__ A, const unsigned short* __restrict__ Bt,
    const float* __restrict__ bias, const float* __restrict__ resid,
    float* __restrict__ outf, unsigned short* __restrict__ outb,
    int M, int N, int K) {
  __shared__ unsigned short lA[128 * 32];
  __shared__ unsigned short lB[128 * 32];
  int tid = threadIdx.x;
  int m0 = blockIdx.y * 128, n0 = blockIdx.x * 128;
  int lane = tid & 63, w = tid >> 6;
  int wm = (w >> 1) * 64, wn = (w & 1) * 64;
  int lr = lane & 15, lg = lane >> 4;
  f32x4 acc[4][4] = {};
  // staging: 8 chunks of 1024B per tile; wave w owns chunks {2w, 2w+1}
  int p0 = w * 128 + lane;        // chunk piece index 0..511 (w*2*64 + lane)
  int p1 = p0 + 64;
  int r0 = p0 >> 2, c0 = (p0 & 3) * 8;
  int r1 = p1 >> 2, c1 = (p1 & 3) * 8;
  const unsigned short* As0 = A + (size_t)(m0 + r0) * K + c0;
  const unsigned short* As1 = A + (size_t)(m0 + r1) * K + c1;
  const unsigned short* Bs0 = Bt + (size_t)(n0 + r0) * K + c0;
  const unsigned short* Bs1 = Bt + (size_t)(n0 + r1) * K + c1;
  unsigned short* dA0 = &lA[(w * 2) * 512];
  unsigned short* dA1 = &lA[(w * 2 + 1) * 512];
  unsigned short* dB0 = &lB[(w * 2) * 512];
  unsigned short* dB1 = &lB[(w * 2 + 1) * 512];
  for (int k0 = 0; k0 < K; k0 += 32) {
    __syncthreads();
    gload_lds16(As0 + k0, dA0);
    gload_lds16(As1 + k0, dA1);
    gload_lds16(Bs0 + k0, dB0);
    gload_lds16(Bs1 + k0, dB1);
    __syncthreads();
    bf16x8 af[4], bfr[4];
#pragma unroll
    for (int i = 0; i < 4; i++) {
      af[i] = *(const bf16x8*)&lA[(wm + i * 16 + lr) * 32 + lg * 8];
      bfr[i] = *(const bf16x8*)&lB[(wn + i * 16 + lr) * 32 + lg * 8];
    }
#pragma unroll
    for (int i = 0; i < 4; i++)
#pragma unroll
      for (int j = 0; j < 4; j++)
        acc[i][j] = MFMA16(af[i], bfr[j], acc[i][j]);
  }
#pragma unroll
  for (int i = 0; i < 4; i++) {
#pragma unroll
    for (int j = 0; j < 4; j++) {
      int colb = n0 + wn + j * 16 + lr;
      float bv = bias[colb];
#pragma unroll
      for (int r = 0; r < 4; r++) {
        int row = m0 + wm + i * 16 + lg * 4 + r;
        float v = acc[i][j][r] + bv;
        size_t idx = (size_t)row * N + colb;
        if constexpr (EPI == 0) {
          outb[idx] = f2bf(v);
        } else if constexpr (EPI == 1) {
          outf[idx] = v + resid[idx];
        } else {
          float gv = 0.5f * v * (1.0f + erff(v * 0.70710678118654752f));
          outb[idx] = f2bf(gv);
        }
      }
    }
  }
}

// ---------------- causal flash attention ----------------
// qkv bf16 [B*T][3072] (Q|K|V). Vt bf16 [BH][64][2048]. out bf16 [B*T][1024].
// grid: x = q-tile (128 rows, reversed), y = b*16+h. 4 waves x 32 q-rows.
__global__ __launch_bounds__(256) void k_attention(
    const unsigned short* __restrict__ qkv, const unsigned short* __restrict__ Vt,
    unsigned short* __restrict__ out) {
  __shared__ unsigned short lK[64 * 64];  // [key][d], XOR-swizzled rows of 128B
  __shared__ unsigned short lV[64 * 64];  // [d][key], XOR-swizzled
  __shared__ unsigned short lP[4][32][68];
  int qt = (gridDim.x - 1) - blockIdx.x;  // big tiles dispatch first
  int bh = blockIdx.y;
  int b = bh >> 4, h = bh & 15;
  int tid = threadIdx.x, lane = tid & 63, w = tid >> 6;
  int lr = lane & 15, lg = lane >> 4;
  const unsigned short* base = qkv + (size_t)b * SEQ * THREE_EMBED + h * HDIM;
  const unsigned short* Kb = base + EMBED;
  const unsigned short* Vb = Vt + (size_t)bh * HDIM * SEQ;
  int q0 = qt * QBLK + w * 32;
  bf16x8 qf[2][2];
#pragma unroll
  for (int qs = 0; qs < 2; qs++) {
    int qrow = q0 + qs * 16 + lr;
    qf[qs][0] = *(const bf16x8*)(base + (size_t)qrow * THREE_EMBED + lg * 8);
    qf[qs][1] = *(const bf16x8*)(base + (size_t)qrow * THREE_EMBED + 32 + lg * 8);
  }
  f32x4 o[2][4] = {};
  float m_[2][4], l_[2][4];
#pragma unroll
  for (int qs = 0; qs < 2; qs++)
#pragma unroll
    for (int r = 0; r < 4; r++) { m_[qs][r] = -INFINITY; l_[qs][r] = 0.f; }
  // staging source pre-swizzle: chunk piece -> (row = chunk*8 + lane/8, col16B = (lane&7)^(lane>>3))
  int srow = lane >> 3;
  int scol = ((lane & 7) ^ (lane >> 3)) * 8;  // shorts
  const float SCL = 0.125f * 1.4426950408889634f;  // 1/sqrt(64) * log2(e)
  int nkv = 2 * qt + 2;
  for (int kt = 0; kt < nkv; kt++) {
    __syncthreads();
#pragma unroll
    for (int c = 0; c < 2; c++) {
      int chunk = w * 2 + c;
      int row = chunk * 8 + srow;
      gload_lds16(Kb + (size_t)(kt * 64 + row) * THREE_EMBED + scol, &lK[chunk * 512]);
      gload_lds16(Vb + (size_t)row * SEQ + kt * 64 + scol, &lV[chunk * 512]);
    }
    __syncthreads();
    if (q0 + 31 < kt * 64) continue;  // wave fully masked: skip compute (no barriers inside)
    // ---- QK^T ----
    f32x4 s[2][4];
#pragma unroll
    for (int ct = 0; ct < 4; ct++) {
      int krow = ct * 16 + lr;
      int sw = (krow & 7) << 3;
      bf16x8 k0 = *(const bf16x8*)&lK[krow * 64 + ((lg * 8) ^ sw)];
      bf16x8 k1 = *(const bf16x8*)&lK[krow * 64 + ((32 + lg * 8) ^ sw)];
#pragma unroll
      for (int qs = 0; qs < 2; qs++) {
        f32x4 z = {};
        z = MFMA16(qf[qs][0], k0, z);
        s[qs][ct] = MFMA16(qf[qs][1], k1, z);
      }
    }
    bool maskt = (kt * 64 + 63 > q0);  // tile may cross the diagonal for this wave
    // ---- online softmax (log2 domain) ----
#pragma unroll
    for (int qs = 0; qs < 2; qs++) {
      float mx[4] = {-INFINITY, -INFINITY, -INFINITY, -INFINITY};
#pragma unroll
      for (int ct = 0; ct < 4; ct++) {
#pragma unroll
        for (int r = 0; r < 4; r++) {
          float sv = s[qs][ct][r] * SCL;
          if (maskt) {
            int kg = kt * 64 + ct * 16 + lr;
            int qg = q0 + qs * 16 + lg * 4 + r;
            if (kg > qg) sv = -INFINITY;
          }
          s[qs][ct][r] = sv;
          mx[r] = fmaxf(mx[r], sv);
        }
      }
#pragma unroll
      for (int r = 0; r < 4; r++) {
        mx[r] = fmaxf(mx[r], __shfl_xor(mx[r], 1));
        mx[r] = fmaxf(mx[r], __shfl_xor(mx[r], 2));
        mx[r] = fmaxf(mx[r], __shfl_xor(mx[r], 4));
        mx[r] = fmaxf(mx[r], __shfl_xor(mx[r], 8));
      }
      float al[4], ps[4];
#pragma unroll
      for (int r = 0; r < 4; r++) {
        float mn = fmaxf(m_[qs][r], mx[r]);
        al[r] = exp2f(m_[qs][r] - mn);
        m_[qs][r] = mn;
        ps[r] = 0.f;
      }
#pragma unroll
      for (int ct = 0; ct < 4; ct++)
#pragma unroll
        for (int r = 0; r < 4; r++) {
          float p = exp2f(s[qs][ct][r] - m_[qs][r]);
          ps[r] += p;
          lP[w][qs * 16 + lg * 4 + r][ct * 16 + lr] = f2bf(p);
        }
#pragma unroll
      for (int r = 0; r < 4; r++) {
        ps[r] += __shfl_xor(ps[r], 1);
        ps[r] += __shfl_xor(ps[r], 2);
        ps[r] += __shfl_xor(ps[r], 4);
        ps[r] += __shfl_xor(ps[r], 8);
        l_[qs][r] = l_[qs][r] * al[r] + ps[r];
      }
#pragma unroll
      for (int dt = 0; dt < 4; dt++)
#pragma unroll
        for (int r = 0; r < 4; r++) o[qs][dt][r] *= al[r];
    }
    // ---- PV ----
#pragma unroll
    for (int ks = 0; ks < 2; ks++) {
      bf16x8 pf[2];
#pragma unroll
      for (int qs = 0; qs < 2; qs++)
        pf[qs] = *(const bf16x8*)&lP[w][qs * 16 + lr][ks * 32 + lg * 8];
#pragma unroll
      for (int dt = 0; dt < 4; dt++) {
        int vrow = dt * 16 + lr;
        int sw = (vrow & 7) << 3;
        bf16x8 vf = *(const bf16x8*)&lV[vrow * 64 + ((ks * 32 + lg * 8) ^ sw)];
#pragma unroll
        for (int qs = 0; qs < 2; qs++)
          o[qs][dt] = MFMA16(pf[qs], vf, o[qs][dt]);
      }
    }
  }
#pragma unroll
  for (int qs = 0; qs < 2; qs++)
#pragma unroll
    for (int dt = 0; dt < 4; dt++)
#pragma unroll
      for (int r = 0; r < 4; r++) {
        int row = q0 + qs * 16 + lg * 4 + r;
        float val = o[qs][dt][r] / l_[qs][r];
        out[(size_t)(b * SEQ + row) * EMBED + h * HDIM + dt * 16 + lr] = f2bf(val);
      }
}

extern "C" void kernel_launch(void* const* d_in, const int* in_sizes, int n_in,
                              void* d_out, int out_size, void* d_ws, size_t ws_size,
                              hipStream_t stream) {
  const float* x      = (const float*)d_in[0];
  const float* ln1_g  = (const float*)d_in[1];
  const float* ln1_b  = (const float*)d_in[2];
  const float* w_attn = (const float*)d_in[3];
  const float* b_attn = (const float*)d_in[4];
  const float* w_proj = (const float*)d_in[5];
  const float* b_proj = (const float*)d_in[6];
  const float* ln2_g  = (const float*)d_in[7];
  const float* ln2_b  = (const float*)d_in[8];
  const float* w_fc   = (const float*)d_in[9];
  const float* b_fc   = (const float*)d_in[10];
  const float* w_fc2  = (const float*)d_in[11];
  const float* b_fc2  = (const float*)d_in[12];
  float* outp = (float*)d_out;

  char* ws = (char*)d_ws;
  unsigned short* wT_attn = (unsigned short*)(ws);             // [3072][1024] bf16, 6 MB
  unsigned short* wT_proj = (unsigned short*)(ws + 6291456);   // [1024][1024] bf16, 2 MB
  unsigned short* wT_fc   = (unsigned short*)(ws + 8388608);   // [4096][1024] bf16, 8 MB
  unsigned short* wT_fc2  = (unsigned short*)(ws + 16777216);  // [1024][4096] bf16, 8 MB
  unsigned short* buf1    = (unsigned short*)(ws + 25165824);  // 8 MB: xln -> attnout -> x2ln
  float*          x1      = (float*)(ws + 33554432);           // 16 MB fp32 (written after attention)
  unsigned short* Vt      = (unsigned short*)(ws + 33554432);  // 8 MB bf16, dead once attention done
  unsigned short* qkv_h   = (unsigned short*)(ws + 50331648);  // 24 MB qkv -> 32 MB h (48..80 MB)

  dim3 blk(256);
  k_transpose_bf16<<<dim3(3072 / 32, 1024 / 32), blk, 0, stream>>>(w_attn, wT_attn, 1024, 3072);
  k_transpose_bf16<<<dim3(1024 / 32, 1024 / 32), blk, 0, stream>>>(w_proj, wT_proj, 1024, 1024);
  k_transpose_bf16<<<dim3(4096 / 32, 1024 / 32), blk, 0, stream>>>(w_fc, wT_fc, 1024, 4096);
  k_transpose_bf16<<<dim3(1024 / 32, 4096 / 32), blk, 0, stream>>>(w_fc2, wT_fc2, 4096, 1024);
  // LN1: x -> xln (buf1)
  k_layernorm<<<dim3(MTOT), blk, 0, stream>>>(x, ln1_g, ln1_b, buf1);
  // QKV
  k_gemm<0><<<dim3(THREE_EMBED / 128, MTOT / 128), blk, 0, stream>>>(
      buf1, wT_attn, b_attn, nullptr, nullptr, qkv_h, MTOT, THREE_EMBED, EMBED);
  // V transpose for attention
  k_transpose_v<<<dim3(SEQ / 32, 2 * BATCH * HEADS), blk, 0, stream>>>(qkv_h, Vt);
  // attention -> attnout (buf1)
  k_attention<<<dim3(SEQ / QBLK, BATCH * HEADS), blk, 0, stream>>>(qkv_h, Vt, buf1);
  // proj + residual: x1 = x + attnout @ w_proj + b_proj   (overwrites Vt region — Vt is dead)
  k_gemm<1><<<dim3(EMBED / 128, MTOT / 128), blk, 0, stream>>>(
      buf1, wT_proj, b_proj, x, x1, nullptr, MTOT, EMBED, EMBED);
  // LN2: x1 -> x2ln (buf1)
  k_layernorm<<<dim3(MTOT), blk, 0, stream>>>(x1, ln2_g, ln2_b, buf1);
  // FC1 + GELU -> qkv_h
  k_gemm<2><<<dim3(4 * EMBED / 128, MTOT / 128), blk, 0, stream>>>(
      buf1, wT_fc, b_fc, nullptr, nullptr, qkv_h, MTOT, 4 * EMBED, EMBED);
  // FC2 + residual -> out
  k_gemm<1><<<dim3(EMBED / 128, MTOT / 128), blk, 0, stream>>>(
      qkv_h, wT_fc2, b_fc2, x1, outp, nullptr, MTOT, EMBED, 4 * EMBED);
}

// Round 4
// 351.554 us; speedup vs baseline: 1.2434x; 1.1034x over previous
//
#include <hip/hip_runtime.h>

#define EMBED 1024
#define THREE_EMBED 3072
#define HEADS 16
#define HDIM 64
#define SEQ 2048
#define BATCH 2
#define MTOT 4096  // B*T
#define QBLK 128

typedef short bf16x8 __attribute__((ext_vector_type(8)));
typedef float f32x4 __attribute__((ext_vector_type(4)));

#define MFMA16(a, b, c) __builtin_amdgcn_mfma_f32_16x16x32_bf16(a, b, c, 0, 0, 0)

__device__ __forceinline__ unsigned short f2bf(float f) {
  union { float f; unsigned int u; } v; v.f = f;
  unsigned int r = v.u + 0x7fffu + ((v.u >> 16) & 1u);
  return (unsigned short)(r >> 16);
}

// async 16B global->LDS. LDS dest is wave-uniform base + lane*16 (HW semantics).
__device__ __forceinline__ void gload_lds16(const unsigned short* g, unsigned short* l) {
  __builtin_amdgcn_global_load_lds(
      (const __attribute__((address_space(1))) void*)g,
      (__attribute__((address_space(3))) void*)l, 16, 0, 0);
}

__device__ __forceinline__ void wait_vm0_barrier() {
  asm volatile("s_waitcnt vmcnt(0)" ::: "memory");
  __builtin_amdgcn_s_barrier();
}

// ---------------- transpose fp32 [K][N] -> bf16 [N][K] ----------------
__global__ __launch_bounds__(256) void k_transpose_bf16(
    const float* __restrict__ in, unsigned short* __restrict__ out, int K, int N) {
  __shared__ float t[32][33];
  int tx = threadIdx.x & 31, ty = threadIdx.x >> 5;
  int n0 = blockIdx.x * 32, k0 = blockIdx.y * 32;
#pragma unroll
  for (int i = 0; i < 32; i += 8)
    t[ty + i][tx] = in[(size_t)(k0 + ty + i) * N + n0 + tx];
  __syncthreads();
#pragma unroll
  for (int i = 0; i < 32; i += 8)
    out[(size_t)(n0 + ty + i) * K + k0 + tx] = f2bf(t[tx][ty + i]);
}

// ---------------- V transpose: qkv V-part -> Vt[bh][64][2048] bf16 ----------------
__global__ __launch_bounds__(256) void k_transpose_v(
    const unsigned short* __restrict__ qkv, unsigned short* __restrict__ Vt) {
  __shared__ unsigned short t[32][33];
  int tx = threadIdx.x & 31, ty = threadIdx.x >> 5;  // 32 x 8
  int t0 = blockIdx.x * 32;
  int d0 = (blockIdx.y & 1) * 32;
  int bh = blockIdx.y >> 1;
  int b = bh >> 4, h = bh & 15;
  const unsigned short* src = qkv + (size_t)b * SEQ * THREE_EMBED + 2 * EMBED + h * HDIM;
#pragma unroll
  for (int i = 0; i < 32; i += 8)
    t[ty + i][tx] = src[(size_t)(t0 + ty + i) * THREE_EMBED + d0 + tx];
  __syncthreads();
  unsigned short* dst = Vt + (size_t)bh * HDIM * SEQ;
#pragma unroll
  for (int i = 0; i < 32; i += 8)
    dst[(size_t)(d0 + ty + i) * SEQ + t0 + tx] = t[tx][ty + i];
}

// ---------------- layernorm fp32 [4096][1024] -> bf16 ----------------
__global__ __launch_bounds__(256) void k_layernorm(
    const float* __restrict__ x, const float* __restrict__ g,
    const float* __restrict__ b, unsigned short* __restrict__ out) {
  int row = blockIdx.x;
  int tid = threadIdx.x;
  const float4 xv = *(const float4*)(x + (size_t)row * EMBED + tid * 4);
  float s = xv.x + xv.y + xv.z + xv.w;
  float sq = xv.x * xv.x + xv.y * xv.y + xv.z * xv.z + xv.w * xv.w;
#pragma unroll
  for (int off = 1; off < 64; off <<= 1) {
    s += __shfl_xor(s, off);
    sq += __shfl_xor(sq, off);
  }
  __shared__ float red[8];
  int w = tid >> 6;
  if ((tid & 63) == 0) { red[w] = s; red[4 + w] = sq; }
  __syncthreads();
  s = red[0] + red[1] + red[2] + red[3];
  sq = red[4] + red[5] + red[6] + red[7];
  float mu = s * (1.0f / EMBED);
  float var = sq * (1.0f / EMBED) - mu * mu;
  float rs = rsqrtf(var + 1e-5f);
  float xs[4] = {xv.x, xv.y, xv.z, xv.w};
  unsigned short o[4];
#pragma unroll
  for (int c = 0; c < 4; c++) {
    int col = tid * 4 + c;
    o[c] = f2bf((xs[c] - mu) * rs * g[col] + b[col]);
  }
  *(ushort4*)(out + (size_t)row * EMBED + tid * 4) = *(const ushort4*)o;
}

// ---------------- bf16 MFMA GEMM, T3-min pipelined: C = A[M,K] @ Bt[N,K]^T ----------------
// BN = 128 (2x2 waves of 64x64) or 64 (4 waves of 32x64 stacked along M).
// EPI 0: +bias -> bf16 out; EPI 1: +bias +resid -> f32; EPI 2: +bias GELU -> bf16
template <int EPI, int BN>
__global__ __launch_bounds__(256) void k_gemm(
    const unsigned short* __restrict__ A, const unsigned short* __restrict__ Bt,
    const float* __restrict__ bias, const float* __restrict__ resid,
    float* __restrict__ outf, unsigned short* __restrict__ outb,
    int M, int N, int K) {
  constexpr int BCH = BN / 16;       // B chunks (1 chunk = 16 rows x 32 cols = 1KB)
  constexpr int CHUNKS = 8 + BCH;    // A always 8 chunks
  constexpr int CPW = CHUNKS / 4;    // chunks per wave
  constexpr int MI = (BN == 128) ? 4 : 2;
  constexpr int NJ = 4;
  __shared__ unsigned short lA[2][128 * 32];
  __shared__ unsigned short lB[2][BN * 32];
  int tid = threadIdx.x;
  // XCD-aware swizzle (nwg % 8 == 0 for all our launches)
  int nwg = gridDim.x * gridDim.y;
  int bid = blockIdx.y * gridDim.x + blockIdx.x;
  int swz = (bid & 7) * (nwg >> 3) + (bid >> 3);
  int m0 = (swz / gridDim.x) * 128, n0 = (swz % gridDim.x) * BN;
  int lane = tid & 63, w = tid >> 6;
  int wm = (BN == 128) ? (w >> 1) * 64 : w * 32;
  int wn = (BN == 128) ? (w & 1) * 64 : 0;
  int lr = lane & 15, lg = lane >> 4;
  f32x4 acc[MI][NJ] = {};
  // staging assignment: wave w owns chunks [w*CPW, w*CPW+CPW)
  const unsigned short* gsrc[CPW];
  int loff[CPW];
  bool isa[CPW];
#pragma unroll
  for (int c0 = 0; c0 < CPW; c0++) {
    int c = w * CPW + c0;
    if (c < 8) {
      int row = c * 16 + (lane >> 2);
      gsrc[c0] = A + (size_t)(m0 + row) * K + (lane & 3) * 8;
      loff[c0] = c * 512;
      isa[c0] = true;
    } else {
      int row = (c - 8) * 16 + (lane >> 2);
      gsrc[c0] = Bt + (size_t)(n0 + row) * K + (lane & 3) * 8;
      loff[c0] = (c - 8) * 512;
      isa[c0] = false;
    }
  }
  auto stage = [&](int k0, int cur) {
#pragma unroll
    for (int c0 = 0; c0 < CPW; c0++)
      gload_lds16(gsrc[c0] + k0, isa[c0] ? &lA[cur][loff[c0]] : &lB[cur][loff[c0]]);
  };
  int nt = K >> 5;
  stage(0, 0);
  wait_vm0_barrier();
  int cur = 0;
  for (int t = 0; t < nt; t++) {
    if (t + 1 < nt) stage((t + 1) * 32, cur ^ 1);
    bf16x8 af[MI], bfr[NJ];
#pragma unroll
    for (int i = 0; i < MI; i++)
      af[i] = *(const bf16x8*)&lA[cur][(wm + i * 16 + lr) * 32 + lg * 8];
#pragma unroll
    for (int j = 0; j < NJ; j++)
      bfr[j] = *(const bf16x8*)&lB[cur][(wn + j * 16 + lr) * 32 + lg * 8];
#pragma unroll
    for (int i = 0; i < MI; i++)
#pragma unroll
      for (int j = 0; j < NJ; j++)
        acc[i][j] = MFMA16(af[i], bfr[j], acc[i][j]);
    wait_vm0_barrier();
    cur ^= 1;
  }
#pragma unroll
  for (int i = 0; i < MI; i++) {
#pragma unroll
    for (int j = 0; j < NJ; j++) {
      int colb = n0 + wn + j * 16 + lr;
      float bv = bias[colb];
#pragma unroll
      for (int r = 0; r < 4; r++) {
        int row = m0 + wm + i * 16 + lg * 4 + r;
        float v = acc[i][j][r] + bv;
        size_t idx = (size_t)row * N + colb;
        if constexpr (EPI == 0) {
          outb[idx] = f2bf(v);
        } else if constexpr (EPI == 1) {
          outf[idx] = v + resid[idx];
        } else {
          float gv = 0.5f * v * (1.0f + erff(v * 0.70710678118654752f));
          outb[idx] = f2bf(gv);
        }
      }
    }
  }
}

// ---------------- causal flash attention (T3-min pipelined) ----------------
// qkv bf16 [B*T][3072] (Q|K|V). Vt bf16 [BH][64][2048]. out bf16 [B*T][1024].
// grid x*y = 16*32 XCD-swizzled; qt reversed (big first). 4 waves x 32 q-rows.
__global__ __launch_bounds__(256) void k_attention(
    const unsigned short* __restrict__ qkv, const unsigned short* __restrict__ Vt,
    unsigned short* __restrict__ out) {
  __shared__ unsigned short lK[2][64 * 64];  // [key][d], rows XOR-swizzled in 16B units
  __shared__ unsigned short lV[2][64 * 64];  // [d][key], XOR-swizzled
  __shared__ unsigned short lP[4][32][68];
  int nwg = gridDim.x * gridDim.y;
  int bid = blockIdx.y * gridDim.x + blockIdx.x;
  int swz = (bid & 7) * (nwg >> 3) + (bid >> 3);
  int qt = (gridDim.x - 1) - (swz % gridDim.x);  // big tiles first within each XCD chunk
  int bh = swz / gridDim.x;
  int b = bh >> 4, h = bh & 15;
  int tid = threadIdx.x, lane = tid & 63, w = tid >> 6;
  int lr = lane & 15, lg = lane >> 4;
  const unsigned short* base = qkv + (size_t)b * SEQ * THREE_EMBED + h * HDIM;
  const unsigned short* Kb = base + EMBED;
  const unsigned short* Vb = Vt + (size_t)bh * HDIM * SEQ;
  int q0 = qt * QBLK + w * 32;
  bf16x8 qf[2][2];
#pragma unroll
  for (int qs = 0; qs < 2; qs++) {
    int qrow = q0 + qs * 16 + lr;
    qf[qs][0] = *(const bf16x8*)(base + (size_t)qrow * THREE_EMBED + lg * 8);
    qf[qs][1] = *(const bf16x8*)(base + (size_t)qrow * THREE_EMBED + 32 + lg * 8);
  }
  f32x4 o[2][4] = {};
  float m_[2][4], l_[2][4];
#pragma unroll
  for (int qs = 0; qs < 2; qs++)
#pragma unroll
    for (int r = 0; r < 4; r++) { m_[qs][r] = -INFINITY; l_[qs][r] = 0.f; }
  // staging: chunk = w*2+c; row = chunk*8 + lane/8; source col pre-swizzled so that
  // linear LDS + swizzled ds_read gives conflict-free 128B rows.
  int srow = lane >> 3;
  int scol = ((lane & 7) ^ (lane >> 3)) * 8;  // shorts
  const float SCL = 0.125f * 1.4426950408889634f;  // 1/sqrt(64) * log2(e)
  int nkv = 2 * qt + 2;
  auto stage = [&](int kt, int cur) {
#pragma unroll
    for (int c = 0; c < 2; c++) {
      int chunk = w * 2 + c;
      int row = chunk * 8 + srow;
      gload_lds16(Kb + (size_t)(kt * 64 + row) * THREE_EMBED + scol, &lK[cur][chunk * 512]);
      gload_lds16(Vb + (size_t)row * SEQ + kt * 64 + scol, &lV[cur][chunk * 512]);
    }
  };
  stage(0, 0);
  wait_vm0_barrier();
  int cur = 0;
  for (int kt = 0; kt < nkv; kt++) {
    if (kt + 1 < nkv) stage(kt + 1, cur ^ 1);
    if (!(q0 + 31 < kt * 64)) {  // wave not fully masked
      // ---- QK^T ----
      f32x4 s[2][4];
#pragma unroll
      for (int ct = 0; ct < 4; ct++) {
        int krow = ct * 16 + lr;
        int sw = (krow & 7) << 3;
        bf16x8 k0 = *(const bf16x8*)&lK[cur][krow * 64 + ((lg * 8) ^ sw)];
        bf16x8 k1 = *(const bf16x8*)&lK[cur][krow * 64 + ((32 + lg * 8) ^ sw)];
#pragma unroll
        for (int qs = 0; qs < 2; qs++) {
          f32x4 z = {};
          z = MFMA16(qf[qs][0], k0, z);
          s[qs][ct] = MFMA16(qf[qs][1], k1, z);
        }
      }
      bool maskt = (kt * 64 + 63 > q0);
      // ---- online softmax (log2 domain) ----
#pragma unroll
      for (int qs = 0; qs < 2; qs++) {
        float mx[4] = {-INFINITY, -INFINITY, -INFINITY, -INFINITY};
#pragma unroll
        for (int ct = 0; ct < 4; ct++) {
#pragma unroll
          for (int r = 0; r < 4; r++) {
            float sv = s[qs][ct][r] * SCL;
            if (maskt) {
              int kg = kt * 64 + ct * 16 + lr;
              int qg = q0 + qs * 16 + lg * 4 + r;
              if (kg > qg) sv = -INFINITY;
            }
            s[qs][ct][r] = sv;
            mx[r] = fmaxf(mx[r], sv);
          }
        }
#pragma unroll
        for (int r = 0; r < 4; r++) {
          mx[r] = fmaxf(mx[r], __shfl_xor(mx[r], 1));
          mx[r] = fmaxf(mx[r], __shfl_xor(mx[r], 2));
          mx[r] = fmaxf(mx[r], __shfl_xor(mx[r], 4));
          mx[r] = fmaxf(mx[r], __shfl_xor(mx[r], 8));
        }
        float al[4], ps[4];
#pragma unroll
        for (int r = 0; r < 4; r++) {
          float mn = fmaxf(m_[qs][r], mx[r]);
          al[r] = exp2f(m_[qs][r] - mn);
          m_[qs][r] = mn;
          ps[r] = 0.f;
        }
#pragma unroll
        for (int ct = 0; ct < 4; ct++)
#pragma unroll
          for (int r = 0; r < 4; r++) {
            float p = exp2f(s[qs][ct][r] - m_[qs][r]);
            ps[r] += p;
            lP[w][qs * 16 + lg * 4 + r][ct * 16 + lr] = f2bf(p);
          }
#pragma unroll
        for (int r = 0; r < 4; r++) {
          ps[r] += __shfl_xor(ps[r], 1);
          ps[r] += __shfl_xor(ps[r], 2);
          ps[r] += __shfl_xor(ps[r], 4);
          ps[r] += __shfl_xor(ps[r], 8);
          l_[qs][r] = l_[qs][r] * al[r] + ps[r];
        }
#pragma unroll
        for (int dt = 0; dt < 4; dt++)
#pragma unroll
          for (int r = 0; r < 4; r++) o[qs][dt][r] *= al[r];
      }
      // ---- PV ----
#pragma unroll
      for (int ks = 0; ks < 2; ks++) {
        bf16x8 pf[2];
#pragma unroll
        for (int qs = 0; qs < 2; qs++)
          pf[qs] = *(const bf16x8*)&lP[w][qs * 16 + lr][ks * 32 + lg * 8];
#pragma unroll
        for (int dt = 0; dt < 4; dt++) {
          int vrow = dt * 16 + lr;
          int sw = (vrow & 7) << 3;
          bf16x8 vf = *(const bf16x8*)&lV[cur][vrow * 64 + ((ks * 32 + lg * 8) ^ sw)];
#pragma unroll
          for (int qs = 0; qs < 2; qs++)
            o[qs][dt] = MFMA16(pf[qs], vf, o[qs][dt]);
        }
      }
    }
    wait_vm0_barrier();
    cur ^= 1;
  }
#pragma unroll
  for (int qs = 0; qs < 2; qs++)
#pragma unroll
    for (int dt = 0; dt < 4; dt++)
#pragma unroll
      for (int r = 0; r < 4; r++) {
        int row = q0 + qs * 16 + lg * 4 + r;
        float val = o[qs][dt][r] / l_[qs][r];
        out[(size_t)(b * SEQ + row) * EMBED + h * HDIM + dt * 16 + lr] = f2bf(val);
      }
}

extern "C" void kernel_launch(void* const* d_in, const int* in_sizes, int n_in,
                              void* d_out, int out_size, void* d_ws, size_t ws_size,
                              hipStream_t stream) {
  const float* x      = (const float*)d_in[0];
  const float* ln1_g  = (const float*)d_in[1];
  const float* ln1_b  = (const float*)d_in[2];
  const float* w_attn = (const float*)d_in[3];
  const float* b_attn = (const float*)d_in[4];
  const float* w_proj = (const float*)d_in[5];
  const float* b_proj = (const float*)d_in[6];
  const float* ln2_g  = (const float*)d_in[7];
  const float* ln2_b  = (const float*)d_in[8];
  const float* w_fc   = (const float*)d_in[9];
  const float* b_fc   = (const float*)d_in[10];
  const float* w_fc2  = (const float*)d_in[11];
  const float* b_fc2  = (const float*)d_in[12];
  float* outp = (float*)d_out;

  char* ws = (char*)d_ws;
  unsigned short* wT_attn = (unsigned short*)(ws);             // [3072][1024] bf16, 6 MB
  unsigned short* wT_proj = (unsigned short*)(ws + 6291456);   // [1024][1024] bf16, 2 MB
  unsigned short* wT_fc   = (unsigned short*)(ws + 8388608);   // [4096][1024] bf16, 8 MB
  unsigned short* wT_fc2  = (unsigned short*)(ws + 16777216);  // [1024][4096] bf16, 8 MB
  unsigned short* buf1    = (unsigned short*)(ws + 25165824);  // 8 MB: xln -> attnout -> x2ln
  float*          x1      = (float*)(ws + 33554432);           // 16 MB fp32 (written after attention)
  unsigned short* Vt      = (unsigned short*)(ws + 33554432);  // 8 MB bf16, dead once attention done
  unsigned short* qkv_h   = (unsigned short*)(ws + 50331648);  // 24 MB qkv -> 32 MB h (48..80 MB)

  dim3 blk(256);
  k_transpose_bf16<<<dim3(3072 / 32, 1024 / 32), blk, 0, stream>>>(w_attn, wT_attn, 1024, 3072);
  k_transpose_bf16<<<dim3(1024 / 32, 1024 / 32), blk, 0, stream>>>(w_proj, wT_proj, 1024, 1024);
  k_transpose_bf16<<<dim3(4096 / 32, 1024 / 32), blk, 0, stream>>>(w_fc, wT_fc, 1024, 4096);
  k_transpose_bf16<<<dim3(1024 / 32, 4096 / 32), blk, 0, stream>>>(w_fc2, wT_fc2, 4096, 1024);
  // LN1: x -> xln (buf1)
  k_layernorm<<<dim3(MTOT), blk, 0, stream>>>(x, ln1_g, ln1_b, buf1);
  // QKV: 24x32 = 768 blocks
  k_gemm<0, 128><<<dim3(THREE_EMBED / 128, MTOT / 128), blk, 0, stream>>>(
      buf1, wT_attn, b_attn, nullptr, nullptr, qkv_h, MTOT, THREE_EMBED, EMBED);
  // V transpose for attention
  k_transpose_v<<<dim3(SEQ / 32, 2 * BATCH * HEADS), blk, 0, stream>>>(qkv_h, Vt);
  // attention -> attnout (buf1): 16x32 = 512 blocks
  k_attention<<<dim3(SEQ / QBLK, BATCH * HEADS), blk, 0, stream>>>(qkv_h, Vt, buf1);
  // proj + residual: narrow tile, 16x32 = 512 blocks (overwrites Vt region — Vt dead)
  k_gemm<1, 64><<<dim3(EMBED / 64, MTOT / 128), blk, 0, stream>>>(
      buf1, wT_proj, b_proj, x, x1, nullptr, MTOT, EMBED, EMBED);
  // LN2: x1 -> x2ln (buf1)
  k_layernorm<<<dim3(MTOT), blk, 0, stream>>>(x1, ln2_g, ln2_b, buf1);
  // FC1 + GELU -> qkv_h: 32x32 = 1024 blocks
  k_gemm<2, 128><<<dim3(4 * EMBED / 128, MTOT / 128), blk, 0, stream>>>(
      buf1, wT_fc, b_fc, nullptr, nullptr, qkv_h, MTOT, 4 * EMBED, EMBED);
  // FC2 + residual -> out: narrow tile, 16x32 = 512 blocks
  k_gemm<1, 64><<<dim3(EMBED / 64, MTOT / 128), blk, 0, stream>>>(
      qkv_h, wT_fc2, b_fc2, x1, outp, nullptr, MTOT, EMBED, 4 * EMBED);
}

// Round 5
// 281.107 us; speedup vs baseline: 1.5550x; 1.2506x over previous
//
#include <hip/hip_runtime.h>

#define EMBED 1024
#define THREE_EMBED 3072
#define HEADS 16
#define HDIM 64
#define SEQ 2048
#define BATCH 2
#define MTOT 4096  // B*T

typedef short bf16x8 __attribute__((ext_vector_type(8)));
typedef float f32x4 __attribute__((ext_vector_type(4)));

#define MFMA16(a, b, c) __builtin_amdgcn_mfma_f32_16x16x32_bf16(a, b, c, 0, 0, 0)

__device__ __forceinline__ unsigned short f2bf(float f) {
  union { float f; unsigned int u; } v; v.f = f;
  unsigned int r = v.u + 0x7fffu + ((v.u >> 16) & 1u);
  return (unsigned short)(r >> 16);
}

// async 16B global->LDS. LDS dest is wave-uniform base + lane*16 (HW semantics).
__device__ __forceinline__ void gload_lds16(const unsigned short* g, unsigned short* l) {
  __builtin_amdgcn_global_load_lds(
      (const __attribute__((address_space(1))) void*)g,
      (__attribute__((address_space(3))) void*)l, 16, 0, 0);
}

__device__ __forceinline__ void wait_vm0_barrier() {
  asm volatile("s_waitcnt vmcnt(0)" ::: "memory");
  __builtin_amdgcn_s_barrier();
}

// ---------------- transpose fp32 [K][N] -> bf16 [N][K] ----------------
__global__ __launch_bounds__(256) void k_transpose_bf16(
    const float* __restrict__ in, unsigned short* __restrict__ out, int K, int N) {
  __shared__ float t[32][33];
  int tx = threadIdx.x & 31, ty = threadIdx.x >> 5;
  int n0 = blockIdx.x * 32, k0 = blockIdx.y * 32;
#pragma unroll
  for (int i = 0; i < 32; i += 8)
    t[ty + i][tx] = in[(size_t)(k0 + ty + i) * N + n0 + tx];
  __syncthreads();
#pragma unroll
  for (int i = 0; i < 32; i += 8)
    out[(size_t)(n0 + ty + i) * K + k0 + tx] = f2bf(t[tx][ty + i]);
}

// ---------------- V transpose: qkv V-part -> Vt[bh][64][2048] bf16 ----------------
__global__ __launch_bounds__(256) void k_transpose_v(
    const unsigned short* __restrict__ qkv, unsigned short* __restrict__ Vt) {
  __shared__ unsigned short t[32][33];
  int tx = threadIdx.x & 31, ty = threadIdx.x >> 5;  // 32 x 8
  int t0 = blockIdx.x * 32;
  int d0 = (blockIdx.y & 1) * 32;
  int bh = blockIdx.y >> 1;
  int b = bh >> 4, h = bh & 15;
  const unsigned short* src = qkv + (size_t)b * SEQ * THREE_EMBED + 2 * EMBED + h * HDIM;
#pragma unroll
  for (int i = 0; i < 32; i += 8)
    t[ty + i][tx] = src[(size_t)(t0 + ty + i) * THREE_EMBED + d0 + tx];
  __syncthreads();
  unsigned short* dst = Vt + (size_t)bh * HDIM * SEQ;
#pragma unroll
  for (int i = 0; i < 32; i += 8)
    dst[(size_t)(d0 + ty + i) * SEQ + t0 + tx] = t[tx][ty + i];
}

// ---------------- layernorm fp32 [4096][1024] -> bf16 ----------------
__global__ __launch_bounds__(256) void k_layernorm(
    const float* __restrict__ x, const float* __restrict__ g,
    const float* __restrict__ b, unsigned short* __restrict__ out) {
  int row = blockIdx.x;
  int tid = threadIdx.x;
  const float4 xv = *(const float4*)(x + (size_t)row * EMBED + tid * 4);
  float s = xv.x + xv.y + xv.z + xv.w;
  float sq = xv.x * xv.x + xv.y * xv.y + xv.z * xv.z + xv.w * xv.w;
#pragma unroll
  for (int off = 1; off < 64; off <<= 1) {
    s += __shfl_xor(s, off);
    sq += __shfl_xor(sq, off);
  }
  __shared__ float red[8];
  int w = tid >> 6;
  if ((tid & 63) == 0) { red[w] = s; red[4 + w] = sq; }
  __syncthreads();
  s = red[0] + red[1] + red[2] + red[3];
  sq = red[4] + red[5] + red[6] + red[7];
  float mu = s * (1.0f / EMBED);
  float var = sq * (1.0f / EMBED) - mu * mu;
  float rs = rsqrtf(var + 1e-5f);
  float xs[4] = {xv.x, xv.y, xv.z, xv.w};
  unsigned short o[4];
#pragma unroll
  for (int c = 0; c < 4; c++) {
    int col = tid * 4 + c;
    o[c] = f2bf((xs[c] - mu) * rs * g[col] + b[col]);
  }
  *(ushort4*)(out + (size_t)row * EMBED + tid * 4) = *(const ushort4*)o;
}

// ---------------- bf16 MFMA GEMM, T3-min pipelined: C = A[M,K] @ Bt[N,K]^T ----------------
// BN = 128 (2x2 waves of 64x64) or 64 (4 waves of 32x64 stacked along M).
// EPI 0: +bias -> bf16 out; EPI 1: +bias +resid -> f32; EPI 2: +bias GELU -> bf16
template <int EPI, int BN>
__global__ __launch_bounds__(256) void k_gemm(
    const unsigned short* __restrict__ A, const unsigned short* __restrict__ Bt,
    const float* __restrict__ bias, const float* __restrict__ resid,
    float* __restrict__ outf, unsigned short* __restrict__ outb,
    int M, int N, int K) {
  constexpr int BCH = BN / 16;       // B chunks (1 chunk = 16 rows x 32 cols = 1KB)
  constexpr int CHUNKS = 8 + BCH;    // A always 8 chunks
  constexpr int CPW = CHUNKS / 4;    // chunks per wave
  constexpr int MI = (BN == 128) ? 4 : 2;
  constexpr int NJ = 4;
  __shared__ unsigned short lA[2][128 * 32];
  __shared__ unsigned short lB[2][BN * 32];
  int tid = threadIdx.x;
  // XCD-aware swizzle (nwg % 8 == 0 for all our launches)
  int nwg = gridDim.x * gridDim.y;
  int bid = blockIdx.y * gridDim.x + blockIdx.x;
  int swz = (bid & 7) * (nwg >> 3) + (bid >> 3);
  int m0 = (swz / gridDim.x) * 128, n0 = (swz % gridDim.x) * BN;
  int lane = tid & 63, w = tid >> 6;
  int wm = (BN == 128) ? (w >> 1) * 64 : w * 32;
  int wn = (BN == 128) ? (w & 1) * 64 : 0;
  int lr = lane & 15, lg = lane >> 4;
  f32x4 acc[MI][NJ] = {};
  // staging assignment: wave w owns chunks [w*CPW, w*CPW+CPW)
  const unsigned short* gsrc[CPW];
  int loff[CPW];
  bool isa[CPW];
#pragma unroll
  for (int c0 = 0; c0 < CPW; c0++) {
    int c = w * CPW + c0;
    if (c < 8) {
      int row = c * 16 + (lane >> 2);
      gsrc[c0] = A + (size_t)(m0 + row) * K + (lane & 3) * 8;
      loff[c0] = c * 512;
      isa[c0] = true;
    } else {
      int row = (c - 8) * 16 + (lane >> 2);
      gsrc[c0] = Bt + (size_t)(n0 + row) * K + (lane & 3) * 8;
      loff[c0] = (c - 8) * 512;
      isa[c0] = false;
    }
  }
  auto stage = [&](int k0, int cur) {
#pragma unroll
    for (int c0 = 0; c0 < CPW; c0++)
      gload_lds16(gsrc[c0] + k0, isa[c0] ? &lA[cur][loff[c0]] : &lB[cur][loff[c0]]);
  };
  int nt = K >> 5;
  stage(0, 0);
  wait_vm0_barrier();
  int cur = 0;
  for (int t = 0; t < nt; t++) {
    if (t + 1 < nt) stage((t + 1) * 32, cur ^ 1);
    bf16x8 af[MI], bfr[NJ];
#pragma unroll
    for (int i = 0; i < MI; i++)
      af[i] = *(const bf16x8*)&lA[cur][(wm + i * 16 + lr) * 32 + lg * 8];
#pragma unroll
    for (int j = 0; j < NJ; j++)
      bfr[j] = *(const bf16x8*)&lB[cur][(wn + j * 16 + lr) * 32 + lg * 8];
#pragma unroll
    for (int i = 0; i < MI; i++)
#pragma unroll
      for (int j = 0; j < NJ; j++)
        acc[i][j] = MFMA16(af[i], bfr[j], acc[i][j]);
    wait_vm0_barrier();
    cur ^= 1;
  }
#pragma unroll
  for (int i = 0; i < MI; i++) {
#pragma unroll
    for (int j = 0; j < NJ; j++) {
      int colb = n0 + wn + j * 16 + lr;
      float bv = bias[colb];
#pragma unroll
      for (int r = 0; r < 4; r++) {
        int row = m0 + wm + i * 16 + lg * 4 + r;
        float v = acc[i][j][r] + bv;
        size_t idx = (size_t)row * N + colb;
        if constexpr (EPI == 0) {
          outb[idx] = f2bf(v);
        } else if constexpr (EPI == 1) {
          outf[idx] = v + resid[idx];
        } else {
          float gv = 0.5f * v * (1.0f + erff(v * 0.70710678118654752f));
          outb[idx] = f2bf(gv);
        }
      }
    }
  }
}

// ---------------- causal flash attention ----------------
// QBLK=64 (4 waves x 16 q-rows), KVBLK=64. Defer-max softmax (T13), row-sum via
// all-ones MFMA column, dbuf K/V staging, explicit XCD x big-first block mapping.
// grid: 1024 blocks. bid -> xcd = bid&7, i = bid>>3; qt = 31-(i>>2); bh = xcd*4+(i&3).
__global__ __launch_bounds__(256) void k_attention(
    const unsigned short* __restrict__ qkv, const unsigned short* __restrict__ Vt,
    unsigned short* __restrict__ out) {
  __shared__ unsigned short lK[2][64 * 64];  // [key][d], rows XOR-swizzled in 16B units
  __shared__ unsigned short lV[2][64 * 64];  // [d][key], XOR-swizzled
  __shared__ unsigned short lP[4][16][72];
  int bid = blockIdx.x;
  int i = bid >> 3;
  int qt = 31 - (i >> 2);                 // big tiles first in dispatch order
  int bh = (bid & 7) * 4 + (i & 3);       // 4 heads per XCD -> K/V L2-resident
  int b = bh >> 4, h = bh & 15;
  int tid = threadIdx.x, lane = tid & 63, w = tid >> 6;
  int lr = lane & 15, lg = lane >> 4;
  const unsigned short* base = qkv + (size_t)b * SEQ * THREE_EMBED + h * HDIM;
  const unsigned short* Kb = base + EMBED;
  const unsigned short* Vb = Vt + (size_t)bh * HDIM * SEQ;
  int q0 = qt * 64 + w * 16;
  bf16x8 qf[2];
  {
    int qrow = q0 + lr;
    qf[0] = *(const bf16x8*)(base + (size_t)qrow * THREE_EMBED + lg * 8);
    qf[1] = *(const bf16x8*)(base + (size_t)qrow * THREE_EMBED + 32 + lg * 8);
  }
  bf16x8 ones;
  {
    short o1 = 0x3F80;  // bf16 1.0
#pragma unroll
    for (int j = 0; j < 8; j++) ones[j] = o1;
  }
  f32x4 o[4] = {};
  f32x4 osum = {};
  float m_[4] = {-INFINITY, -INFINITY, -INFINITY, -INFINITY};
  // staging: chunk = w*2+c; row = chunk*8 + lane/8; source col pre-swizzled so that
  // linear LDS + swizzled ds_read gives conflict-free 128B rows.
  int srow = lane >> 3;
  int scol = ((lane & 7) ^ (lane >> 3)) * 8;  // shorts
  const float SCL = 0.125f * 1.4426950408889634f;  // 1/sqrt(64) * log2(e)
  int nkv = qt + 1;
  auto stage = [&](int kt, int cur) {
#pragma unroll
    for (int c = 0; c < 2; c++) {
      int chunk = w * 2 + c;
      int row = chunk * 8 + srow;
      gload_lds16(Kb + (size_t)(kt * 64 + row) * THREE_EMBED + scol, &lK[cur][chunk * 512]);
      gload_lds16(Vb + (size_t)row * SEQ + kt * 64 + scol, &lV[cur][chunk * 512]);
    }
  };
  stage(0, 0);
  wait_vm0_barrier();
  int cur = 0;
  for (int kt = 0; kt < nkv; kt++) {
    if (kt + 1 < nkv) stage(kt + 1, cur ^ 1);
    __builtin_amdgcn_s_setprio(1);
    // ---- QK^T ----
    f32x4 s[4];
#pragma unroll
    for (int ct = 0; ct < 4; ct++) {
      int krow = ct * 16 + lr;
      int sw = (krow & 7) << 3;
      bf16x8 k0 = *(const bf16x8*)&lK[cur][krow * 64 + ((lg * 8) ^ sw)];
      bf16x8 k1 = *(const bf16x8*)&lK[cur][krow * 64 + ((32 + lg * 8) ^ sw)];
      f32x4 z = {};
      z = MFMA16(qf[0], k0, z);
      s[ct] = MFMA16(qf[1], k1, z);
    }
    __builtin_amdgcn_s_setprio(0);
    // ---- scale + causal mask + per-lane partial max ----
    bool maskt = (kt * 64 + 63 > q0);  // only the diagonal tile
    float pm[4] = {-INFINITY, -INFINITY, -INFINITY, -INFINITY};
#pragma unroll
    for (int ct = 0; ct < 4; ct++) {
#pragma unroll
      for (int r = 0; r < 4; r++) {
        float sv = s[ct][r] * SCL;
        if (maskt) {
          int kg = kt * 64 + ct * 16 + lr;
          int qg = q0 + lg * 4 + r;
          if (kg > qg) sv = -INFINITY;
        }
        s[ct][r] = sv;
        pm[r] = fmaxf(pm[r], sv);
      }
    }
    // ---- defer-max check (T13): full reduce+rescale only if max grew > 8 ----
    float dm = fmaxf(fmaxf(pm[0] - m_[0], pm[1] - m_[1]),
                     fmaxf(pm[2] - m_[2], pm[3] - m_[3]));
    if (!__all(dm <= 8.0f)) {
#pragma unroll
      for (int r = 0; r < 4; r++) {
        float mx = pm[r];
        mx = fmaxf(mx, __shfl_xor(mx, 1));
        mx = fmaxf(mx, __shfl_xor(mx, 2));
        mx = fmaxf(mx, __shfl_xor(mx, 4));
        mx = fmaxf(mx, __shfl_xor(mx, 8));
        float mn = fmaxf(m_[r], mx);
        float al = exp2f(m_[r] - mn);
        m_[r] = mn;
        osum[r] *= al;
#pragma unroll
        for (int dt = 0; dt < 4; dt++) o[dt][r] *= al;
      }
    }
    // ---- P = exp2(S - m), write to LDS for PV fragment ----
#pragma unroll
    for (int ct = 0; ct < 4; ct++)
#pragma unroll
      for (int r = 0; r < 4; r++)
        lP[w][lg * 4 + r][ct * 16 + lr] = f2bf(exp2f(s[ct][r] - m_[r]));
    // ---- PV (+ row-sum via all-ones column) ----
    __builtin_amdgcn_s_setprio(1);
#pragma unroll
    for (int ks = 0; ks < 2; ks++) {
      bf16x8 pf = *(const bf16x8*)&lP[w][lr][ks * 32 + lg * 8];
      osum = MFMA16(pf, ones, osum);
#pragma unroll
      for (int dt = 0; dt < 4; dt++) {
        int vrow = dt * 16 + lr;
        int sw = (vrow & 7) << 3;
        bf16x8 vf = *(const bf16x8*)&lV[cur][vrow * 64 + ((ks * 32 + lg * 8) ^ sw)];
        o[dt] = MFMA16(pf, vf, o[dt]);
      }
    }
    __builtin_amdgcn_s_setprio(0);
    wait_vm0_barrier();
    cur ^= 1;
  }
#pragma unroll
  for (int dt = 0; dt < 4; dt++)
#pragma unroll
    for (int r = 0; r < 4; r++) {
      int row = q0 + lg * 4 + r;
      float val = o[dt][r] / osum[r];
      out[(size_t)(b * SEQ + row) * EMBED + h * HDIM + dt * 16 + lr] = f2bf(val);
    }
}

extern "C" void kernel_launch(void* const* d_in, const int* in_sizes, int n_in,
                              void* d_out, int out_size, void* d_ws, size_t ws_size,
                              hipStream_t stream) {
  const float* x      = (const float*)d_in[0];
  const float* ln1_g  = (const float*)d_in[1];
  const float* ln1_b  = (const float*)d_in[2];
  const float* w_attn = (const float*)d_in[3];
  const float* b_attn = (const float*)d_in[4];
  const float* w_proj = (const float*)d_in[5];
  const float* b_proj = (const float*)d_in[6];
  const float* ln2_g  = (const float*)d_in[7];
  const float* ln2_b  = (const float*)d_in[8];
  const float* w_fc   = (const float*)d_in[9];
  const float* b_fc   = (const float*)d_in[10];
  const float* w_fc2  = (const float*)d_in[11];
  const float* b_fc2  = (const float*)d_in[12];
  float* outp = (float*)d_out;

  char* ws = (char*)d_ws;
  unsigned short* wT_attn = (unsigned short*)(ws);             // [3072][1024] bf16, 6 MB
  unsigned short* wT_proj = (unsigned short*)(ws + 6291456);   // [1024][1024] bf16, 2 MB
  unsigned short* wT_fc   = (unsigned short*)(ws + 8388608);   // [4096][1024] bf16, 8 MB
  unsigned short* wT_fc2  = (unsigned short*)(ws + 16777216);  // [1024][4096] bf16, 8 MB
  unsigned short* buf1    = (unsigned short*)(ws + 25165824);  // 8 MB: xln -> attnout -> x2ln
  float*          x1      = (float*)(ws + 33554432);           // 16 MB fp32 (written after attention)
  unsigned short* Vt      = (unsigned short*)(ws + 33554432);  // 8 MB bf16, dead once attention done
  unsigned short* qkv_h   = (unsigned short*)(ws + 50331648);  // 24 MB qkv -> 32 MB h (48..80 MB)

  dim3 blk(256);
  k_transpose_bf16<<<dim3(3072 / 32, 1024 / 32), blk, 0, stream>>>(w_attn, wT_attn, 1024, 3072);
  k_transpose_bf16<<<dim3(1024 / 32, 1024 / 32), blk, 0, stream>>>(w_proj, wT_proj, 1024, 1024);
  k_transpose_bf16<<<dim3(4096 / 32, 1024 / 32), blk, 0, stream>>>(w_fc, wT_fc, 1024, 4096);
  k_transpose_bf16<<<dim3(1024 / 32, 4096 / 32), blk, 0, stream>>>(w_fc2, wT_fc2, 4096, 1024);
  // LN1: x -> xln (buf1)
  k_layernorm<<<dim3(MTOT), blk, 0, stream>>>(x, ln1_g, ln1_b, buf1);
  // QKV: 24x32 = 768 blocks
  k_gemm<0, 128><<<dim3(THREE_EMBED / 128, MTOT / 128), blk, 0, stream>>>(
      buf1, wT_attn, b_attn, nullptr, nullptr, qkv_h, MTOT, THREE_EMBED, EMBED);
  // V transpose for attention
  k_transpose_v<<<dim3(SEQ / 32, 2 * BATCH * HEADS), blk, 0, stream>>>(qkv_h, Vt);
  // attention -> attnout (buf1): 32 q-tiles x 32 bh = 1024 blocks, balanced mapping
  k_attention<<<dim3(1024), blk, 0, stream>>>(qkv_h, Vt, buf1);
  // proj + residual: narrow tile, 16x32 = 512 blocks (overwrites Vt region — Vt dead)
  k_gemm<1, 64><<<dim3(EMBED / 64, MTOT / 128), blk, 0, stream>>>(
      buf1, wT_proj, b_proj, x, x1, nullptr, MTOT, EMBED, EMBED);
  // LN2: x1 -> x2ln (buf1)
  k_layernorm<<<dim3(MTOT), blk, 0, stream>>>(x1, ln2_g, ln2_b, buf1);
  // FC1 + GELU -> qkv_h: 32x32 = 1024 blocks
  k_gemm<2, 128><<<dim3(4 * EMBED / 128, MTOT / 128), blk, 0, stream>>>(
      buf1, wT_fc, b_fc, nullptr, nullptr, qkv_h, MTOT, 4 * EMBED, EMBED);
  // FC2 + residual -> out: narrow tile, 16x32 = 512 blocks
  k_gemm<1, 64><<<dim3(EMBED / 64, MTOT / 128), blk, 0, stream>>>(
      qkv_h, wT_fc2, b_fc2, x1, outp, nullptr, MTOT, EMBED, 4 * EMBED);
}

// Round 6
// 279.317 us; speedup vs baseline: 1.5650x; 1.0064x over previous
//
#include <hip/hip_runtime.h>

#define EMBED 1024
#define THREE_EMBED 3072
#define HEADS 16
#define HDIM 64
#define SEQ 2048
#define BATCH 2
#define MTOT 4096  // B*T

typedef short bf16x8 __attribute__((ext_vector_type(8)));
typedef float f32x4 __attribute__((ext_vector_type(4)));

#define MFMA16(a, b, c) __builtin_amdgcn_mfma_f32_16x16x32_bf16(a, b, c, 0, 0, 0)

__device__ __forceinline__ unsigned short f2bf(float f) {
  union { float f; unsigned int u; } v; v.f = f;
  unsigned int r = v.u + 0x7fffu + ((v.u >> 16) & 1u);
  return (unsigned short)(r >> 16);
}

// async 16B global->LDS. LDS dest is wave-uniform base + lane*16 (HW semantics).
__device__ __forceinline__ void gload_lds16(const unsigned short* g, unsigned short* l) {
  __builtin_amdgcn_global_load_lds(
      (const __attribute__((address_space(1))) void*)g,
      (__attribute__((address_space(3))) void*)l, 16, 0, 0);
}

__device__ __forceinline__ void wait_vm0_barrier() {
  asm volatile("s_waitcnt vmcnt(0)" ::: "memory");
  __builtin_amdgcn_s_barrier();
}

// ---------------- transpose fp32 [K][N] -> bf16 [N][K] ----------------
__global__ __launch_bounds__(256) void k_transpose_bf16(
    const float* __restrict__ in, unsigned short* __restrict__ out, int K, int N) {
  __shared__ float t[32][33];
  int tx = threadIdx.x & 31, ty = threadIdx.x >> 5;
  int n0 = blockIdx.x * 32, k0 = blockIdx.y * 32;
#pragma unroll
  for (int i = 0; i < 32; i += 8)
    t[ty + i][tx] = in[(size_t)(k0 + ty + i) * N + n0 + tx];
  __syncthreads();
#pragma unroll
  for (int i = 0; i < 32; i += 8)
    out[(size_t)(n0 + ty + i) * K + k0 + tx] = f2bf(t[tx][ty + i]);
}

// ---------------- V transpose: qkv V-part -> Vt[bh][64][2048] bf16 ----------------
__global__ __launch_bounds__(256) void k_transpose_v(
    const unsigned short* __restrict__ qkv, unsigned short* __restrict__ Vt) {
  __shared__ unsigned short t[32][33];
  int tx = threadIdx.x & 31, ty = threadIdx.x >> 5;  // 32 x 8
  int t0 = blockIdx.x * 32;
  int d0 = (blockIdx.y & 1) * 32;
  int bh = blockIdx.y >> 1;
  int b = bh >> 4, h = bh & 15;
  const unsigned short* src = qkv + (size_t)b * SEQ * THREE_EMBED + 2 * EMBED + h * HDIM;
#pragma unroll
  for (int i = 0; i < 32; i += 8)
    t[ty + i][tx] = src[(size_t)(t0 + ty + i) * THREE_EMBED + d0 + tx];
  __syncthreads();
  unsigned short* dst = Vt + (size_t)bh * HDIM * SEQ;
#pragma unroll
  for (int i = 0; i < 32; i += 8)
    dst[(size_t)(d0 + ty + i) * SEQ + t0 + tx] = t[tx][ty + i];
}

// ---------------- layernorm fp32 [4096][1024] -> bf16 ----------------
__global__ __launch_bounds__(256) void k_layernorm(
    const float* __restrict__ x, const float* __restrict__ g,
    const float* __restrict__ b, unsigned short* __restrict__ out) {
  int row = blockIdx.x;
  int tid = threadIdx.x;
  const float4 xv = *(const float4*)(x + (size_t)row * EMBED + tid * 4);
  float s = xv.x + xv.y + xv.z + xv.w;
  float sq = xv.x * xv.x + xv.y * xv.y + xv.z * xv.z + xv.w * xv.w;
#pragma unroll
  for (int off = 1; off < 64; off <<= 1) {
    s += __shfl_xor(s, off);
    sq += __shfl_xor(sq, off);
  }
  __shared__ float red[8];
  int w = tid >> 6;
  if ((tid & 63) == 0) { red[w] = s; red[4 + w] = sq; }
  __syncthreads();
  s = red[0] + red[1] + red[2] + red[3];
  sq = red[4] + red[5] + red[6] + red[7];
  float mu = s * (1.0f / EMBED);
  float var = sq * (1.0f / EMBED) - mu * mu;
  float rs = rsqrtf(var + 1e-5f);
  float xs[4] = {xv.x, xv.y, xv.z, xv.w};
  unsigned short o[4];
#pragma unroll
  for (int c = 0; c < 4; c++) {
    int col = tid * 4 + c;
    o[c] = f2bf((xs[c] - mu) * rs * g[col] + b[col]);
  }
  *(ushort4*)(out + (size_t)row * EMBED + tid * 4) = *(const ushort4*)o;
}

// ---------------- bf16 MFMA GEMM, T3-min pipelined + T2 swizzle ----------------
// C = A[M,K] @ Bt[N,K]^T. Rows in LDS are 64B (32 shorts = 4 x 16B slots).
// Swizzle: stored slot = slot ^ ((row>>1)&3)  -> 2-way bank aliasing (free, m136).
// Staging pre-swizzles the GLOBAL source column (linear LDS dest, rule #21).
// BN = 128 (2x2 waves of 64x64) or 64 (4 waves of 32x64 stacked along M).
// EPI 0: +bias -> bf16 out; EPI 1: +bias +resid -> f32; EPI 2: +bias GELU -> bf16
template <int EPI, int BN>
__global__ __launch_bounds__(256) void k_gemm(
    const unsigned short* __restrict__ A, const unsigned short* __restrict__ Bt,
    const float* __restrict__ bias, const float* __restrict__ resid,
    float* __restrict__ outf, unsigned short* __restrict__ outb,
    int M, int N, int K) {
  constexpr int BCH = BN / 16;       // B chunks (1 chunk = 16 rows x 32 cols = 1KB)
  constexpr int CHUNKS = 8 + BCH;    // A always 8 chunks
  constexpr int CPW = CHUNKS / 4;    // chunks per wave
  constexpr int MI = (BN == 128) ? 4 : 2;
  constexpr int NJ = 4;
  __shared__ unsigned short lA[2][128 * 32];
  __shared__ unsigned short lB[2][BN * 32];
  int tid = threadIdx.x;
  // XCD-aware swizzle (nwg % 8 == 0 for all our launches)
  int nwg = gridDim.x * gridDim.y;
  int bid = blockIdx.y * gridDim.x + blockIdx.x;
  int swz = (bid & 7) * (nwg >> 3) + (bid >> 3);
  int m0 = (swz / gridDim.x) * 128, n0 = (swz % gridDim.x) * BN;
  int lane = tid & 63, w = tid >> 6;
  int wm = (BN == 128) ? (w >> 1) * 64 : w * 32;
  int wn = (BN == 128) ? (w & 1) * 64 : 0;
  int lr = lane & 15, lg = lane >> 4;
  f32x4 acc[MI][NJ] = {};
  // staging: wave w owns chunks [w*CPW, w*CPW+CPW). Lane l writes LDS slot (l&3) of
  // chunk-row (l>>2); pre-swizzled global col so LDS holds slot ^ ((row>>1)&3).
  int scol = ((lane & 3) ^ ((lane >> 3) & 3)) * 8;  // shorts
  const unsigned short* gsrc[CPW];
  int loff[CPW];
  bool isa[CPW];
#pragma unroll
  for (int c0 = 0; c0 < CPW; c0++) {
    int c = w * CPW + c0;
    if (c < 8) {
      int row = c * 16 + (lane >> 2);
      gsrc[c0] = A + (size_t)(m0 + row) * K + scol;
      loff[c0] = c * 512;
      isa[c0] = true;
    } else {
      int row = (c - 8) * 16 + (lane >> 2);
      gsrc[c0] = Bt + (size_t)(n0 + row) * K + scol;
      loff[c0] = (c - 8) * 512;
      isa[c0] = false;
    }
  }
  auto stage = [&](int k0, int cur) {
#pragma unroll
    for (int c0 = 0; c0 < CPW; c0++)
      gload_lds16(gsrc[c0] + k0, isa[c0] ? &lA[cur][loff[c0]] : &lB[cur][loff[c0]]);
  };
  // fragment-read swizzled col: (row>>1)&3 == (lr>>1)&3 since wm, i*16 are 0 mod 8
  int fcol = (lg ^ ((lr >> 1) & 3)) * 8;  // shorts
  int nt = K >> 5;
  stage(0, 0);
  wait_vm0_barrier();
  int cur = 0;
  for (int t = 0; t < nt; t++) {
    if (t + 1 < nt) stage((t + 1) * 32, cur ^ 1);
    bf16x8 af[MI], bfr[NJ];
#pragma unroll
    for (int i = 0; i < MI; i++)
      af[i] = *(const bf16x8*)&lA[cur][(wm + i * 16 + lr) * 32 + fcol];
#pragma unroll
    for (int j = 0; j < NJ; j++)
      bfr[j] = *(const bf16x8*)&lB[cur][(wn + j * 16 + lr) * 32 + fcol];
#pragma unroll
    for (int i = 0; i < MI; i++)
#pragma unroll
      for (int j = 0; j < NJ; j++)
        acc[i][j] = MFMA16(af[i], bfr[j], acc[i][j]);
    wait_vm0_barrier();
    cur ^= 1;
  }
#pragma unroll
  for (int i = 0; i < MI; i++) {
#pragma unroll
    for (int j = 0; j < NJ; j++) {
      int colb = n0 + wn + j * 16 + lr;
      float bv = bias[colb];
#pragma unroll
      for (int r = 0; r < 4; r++) {
        int row = m0 + wm + i * 16 + lg * 4 + r;
        float v = acc[i][j][r] + bv;
        size_t idx = (size_t)row * N + colb;
        if constexpr (EPI == 0) {
          outb[idx] = f2bf(v);
        } else if constexpr (EPI == 1) {
          outf[idx] = v + resid[idx];
        } else {
          float gv = 0.5f * v * (1.0f + erff(v * 0.70710678118654752f));
          outb[idx] = f2bf(gv);
        }
      }
    }
  }
}

// ---------------- causal flash attention ----------------
// QBLK=64 (4 waves x 16 q-rows), KVBLK=64. Defer-max softmax (T13), row-sum via
// all-ones MFMA column, dbuf K/V staging, explicit XCD x big-first block mapping.
// grid: 1024 blocks. bid -> xcd = bid&7, i = bid>>3; qt = 31-(i>>2); bh = xcd*4+(i&3).
__global__ __launch_bounds__(256) void k_attention(
    const unsigned short* __restrict__ qkv, const unsigned short* __restrict__ Vt,
    unsigned short* __restrict__ out) {
  __shared__ unsigned short lK[2][64 * 64];  // [key][d], rows XOR-swizzled in 16B units
  __shared__ unsigned short lV[2][64 * 64];  // [d][key], XOR-swizzled
  __shared__ unsigned short lP[4][16][72];
  int bid = blockIdx.x;
  int i = bid >> 3;
  int qt = 31 - (i >> 2);                 // big tiles first in dispatch order
  int bh = (bid & 7) * 4 + (i & 3);       // 4 heads per XCD -> K/V L2-resident
  int b = bh >> 4, h = bh & 15;
  int tid = threadIdx.x, lane = tid & 63, w = tid >> 6;
  int lr = lane & 15, lg = lane >> 4;
  const unsigned short* base = qkv + (size_t)b * SEQ * THREE_EMBED + h * HDIM;
  const unsigned short* Kb = base + EMBED;
  const unsigned short* Vb = Vt + (size_t)bh * HDIM * SEQ;
  int q0 = qt * 64 + w * 16;
  bf16x8 qf[2];
  {
    int qrow = q0 + lr;
    qf[0] = *(const bf16x8*)(base + (size_t)qrow * THREE_EMBED + lg * 8);
    qf[1] = *(const bf16x8*)(base + (size_t)qrow * THREE_EMBED + 32 + lg * 8);
  }
  bf16x8 ones;
  {
    short o1 = 0x3F80;  // bf16 1.0
#pragma unroll
    for (int j = 0; j < 8; j++) ones[j] = o1;
  }
  f32x4 o[4] = {};
  f32x4 osum = {};
  float m_[4] = {-INFINITY, -INFINITY, -INFINITY, -INFINITY};
  // staging: chunk = w*2+c; row = chunk*8 + lane/8; source col pre-swizzled so that
  // linear LDS + swizzled ds_read gives conflict-free 128B rows.
  int srow = lane >> 3;
  int scol = ((lane & 7) ^ (lane >> 3)) * 8;  // shorts
  const float SCL = 0.125f * 1.4426950408889634f;  // 1/sqrt(64) * log2(e)
  int nkv = qt + 1;
  auto stage = [&](int kt, int cur) {
#pragma unroll
    for (int c = 0; c < 2; c++) {
      int chunk = w * 2 + c;
      int row = chunk * 8 + srow;
      gload_lds16(Kb + (size_t)(kt * 64 + row) * THREE_EMBED + scol, &lK[cur][chunk * 512]);
      gload_lds16(Vb + (size_t)row * SEQ + kt * 64 + scol, &lV[cur][chunk * 512]);
    }
  };
  stage(0, 0);
  wait_vm0_barrier();
  int cur = 0;
  for (int kt = 0; kt < nkv; kt++) {
    if (kt + 1 < nkv) stage(kt + 1, cur ^ 1);
    __builtin_amdgcn_s_setprio(1);
    // ---- QK^T ----
    f32x4 s[4];
#pragma unroll
    for (int ct = 0; ct < 4; ct++) {
      int krow = ct * 16 + lr;
      int sw = (krow & 7) << 3;
      bf16x8 k0 = *(const bf16x8*)&lK[cur][krow * 64 + ((lg * 8) ^ sw)];
      bf16x8 k1 = *(const bf16x8*)&lK[cur][krow * 64 + ((32 + lg * 8) ^ sw)];
      f32x4 z = {};
      z = MFMA16(qf[0], k0, z);
      s[ct] = MFMA16(qf[1], k1, z);
    }
    __builtin_amdgcn_s_setprio(0);
    // ---- scale + causal mask + per-lane partial max ----
    bool maskt = (kt * 64 + 63 > q0);  // only the diagonal tile
    float pm[4] = {-INFINITY, -INFINITY, -INFINITY, -INFINITY};
#pragma unroll
    for (int ct = 0; ct < 4; ct++) {
#pragma unroll
      for (int r = 0; r < 4; r++) {
        float sv = s[ct][r] * SCL;
        if (maskt) {
          int kg = kt * 64 + ct * 16 + lr;
          int qg = q0 + lg * 4 + r;
          if (kg > qg) sv = -INFINITY;
        }
        s[ct][r] = sv;
        pm[r] = fmaxf(pm[r], sv);
      }
    }
    // ---- defer-max check (T13): full reduce+rescale only if max grew > 8 ----
    float dm = fmaxf(fmaxf(pm[0] - m_[0], pm[1] - m_[1]),
                     fmaxf(pm[2] - m_[2], pm[3] - m_[3]));
    if (!__all(dm <= 8.0f)) {
#pragma unroll
      for (int r = 0; r < 4; r++) {
        float mx = pm[r];
        mx = fmaxf(mx, __shfl_xor(mx, 1));
        mx = fmaxf(mx, __shfl_xor(mx, 2));
        mx = fmaxf(mx, __shfl_xor(mx, 4));
        mx = fmaxf(mx, __shfl_xor(mx, 8));
        float mn = fmaxf(m_[r], mx);
        float al = exp2f(m_[r] - mn);
        m_[r] = mn;
        osum[r] *= al;
#pragma unroll
        for (int dt = 0; dt < 4; dt++) o[dt][r] *= al;
      }
    }
    // ---- P = exp2(S - m), write to LDS for PV fragment ----
#pragma unroll
    for (int ct = 0; ct < 4; ct++)
#pragma unroll
      for (int r = 0; r < 4; r++)
        lP[w][lg * 4 + r][ct * 16 + lr] = f2bf(exp2f(s[ct][r] - m_[r]));
    // ---- PV (+ row-sum via all-ones column) ----
    __builtin_amdgcn_s_setprio(1);
#pragma unroll
    for (int ks = 0; ks < 2; ks++) {
      bf16x8 pf = *(const bf16x8*)&lP[w][lr][ks * 32 + lg * 8];
      osum = MFMA16(pf, ones, osum);
#pragma unroll
      for (int dt = 0; dt < 4; dt++) {
        int vrow = dt * 16 + lr;
        int sw = (vrow & 7) << 3;
        bf16x8 vf = *(const bf16x8*)&lV[cur][vrow * 64 + ((ks * 32 + lg * 8) ^ sw)];
        o[dt] = MFMA16(pf, vf, o[dt]);
      }
    }
    __builtin_amdgcn_s_setprio(0);
    wait_vm0_barrier();
    cur ^= 1;
  }
#pragma unroll
  for (int dt = 0; dt < 4; dt++)
#pragma unroll
    for (int r = 0; r < 4; r++) {
      int row = q0 + lg * 4 + r;
      float val = o[dt][r] / osum[r];
      out[(size_t)(b * SEQ + row) * EMBED + h * HDIM + dt * 16 + lr] = f2bf(val);
    }
}

extern "C" void kernel_launch(void* const* d_in, const int* in_sizes, int n_in,
                              void* d_out, int out_size, void* d_ws, size_t ws_size,
                              hipStream_t stream) {
  const float* x      = (const float*)d_in[0];
  const float* ln1_g  = (const float*)d_in[1];
  const float* ln1_b  = (const float*)d_in[2];
  const float* w_attn = (const float*)d_in[3];
  const float* b_attn = (const float*)d_in[4];
  const float* w_proj = (const float*)d_in[5];
  const float* b_proj = (const float*)d_in[6];
  const float* ln2_g  = (const float*)d_in[7];
  const float* ln2_b  = (const float*)d_in[8];
  const float* w_fc   = (const float*)d_in[9];
  const float* b_fc   = (const float*)d_in[10];
  const float* w_fc2  = (const float*)d_in[11];
  const float* b_fc2  = (const float*)d_in[12];
  float* outp = (float*)d_out;

  char* ws = (char*)d_ws;
  unsigned short* wT_attn = (unsigned short*)(ws);             // [3072][1024] bf16, 6 MB
  unsigned short* wT_proj = (unsigned short*)(ws + 6291456);   // [1024][1024] bf16, 2 MB
  unsigned short* wT_fc   = (unsigned short*)(ws + 8388608);   // [4096][1024] bf16, 8 MB
  unsigned short* wT_fc2  = (unsigned short*)(ws + 16777216);  // [1024][4096] bf16, 8 MB
  unsigned short* buf1    = (unsigned short*)(ws + 25165824);  // 8 MB: xln -> attnout -> x2ln
  float*          x1      = (float*)(ws + 33554432);           // 16 MB fp32 (written after attention)
  unsigned short* Vt      = (unsigned short*)(ws + 33554432);  // 8 MB bf16, dead once attention done
  unsigned short* qkv_h   = (unsigned short*)(ws + 50331648);  // 24 MB qkv -> 32 MB h (48..80 MB)

  dim3 blk(256);
  k_transpose_bf16<<<dim3(3072 / 32, 1024 / 32), blk, 0, stream>>>(w_attn, wT_attn, 1024, 3072);
  k_transpose_bf16<<<dim3(1024 / 32, 1024 / 32), blk, 0, stream>>>(w_proj, wT_proj, 1024, 1024);
  k_transpose_bf16<<<dim3(4096 / 32, 1024 / 32), blk, 0, stream>>>(w_fc, wT_fc, 1024, 4096);
  k_transpose_bf16<<<dim3(1024 / 32, 4096 / 32), blk, 0, stream>>>(w_fc2, wT_fc2, 4096, 1024);
  // LN1: x -> xln (buf1)
  k_layernorm<<<dim3(MTOT), blk, 0, stream>>>(x, ln1_g, ln1_b, buf1);
  // QKV: 24x32 = 768 blocks
  k_gemm<0, 128><<<dim3(THREE_EMBED / 128, MTOT / 128), blk, 0, stream>>>(
      buf1, wT_attn, b_attn, nullptr, nullptr, qkv_h, MTOT, THREE_EMBED, EMBED);
  // V transpose for attention
  k_transpose_v<<<dim3(SEQ / 32, 2 * BATCH * HEADS), blk, 0, stream>>>(qkv_h, Vt);
  // attention -> attnout (buf1): 32 q-tiles x 32 bh = 1024 blocks, balanced mapping
  k_attention<<<dim3(1024), blk, 0, stream>>>(qkv_h, Vt, buf1);
  // proj + residual: narrow tile, 16x32 = 512 blocks (overwrites Vt region — Vt dead)
  k_gemm<1, 64><<<dim3(EMBED / 64, MTOT / 128), blk, 0, stream>>>(
      buf1, wT_proj, b_proj, x, x1, nullptr, MTOT, EMBED, EMBED);
  // LN2: x1 -> x2ln (buf1)
  k_layernorm<<<dim3(MTOT), blk, 0, stream>>>(x1, ln2_g, ln2_b, buf1);
  // FC1 + GELU -> qkv_h: 32x32 = 1024 blocks
  k_gemm<2, 128><<<dim3(4 * EMBED / 128, MTOT / 128), blk, 0, stream>>>(
      buf1, wT_fc, b_fc, nullptr, nullptr, qkv_h, MTOT, 4 * EMBED, EMBED);
  // FC2 + residual -> out: narrow tile, 16x32 = 512 blocks
  k_gemm<1, 64><<<dim3(EMBED / 64, MTOT / 128), blk, 0, stream>>>(
      qkv_h, wT_fc2, b_fc2, x1, outp, nullptr, MTOT, EMBED, 4 * EMBED);
}